// Round 1
// baseline (1076.078 us; speedup 1.0000x reference)
//
#include <hip/hip_runtime.h>

// LocalAttention: windowed MHA, fully fused, bf16 MFMA.
// B=8, C=512, H=W=128, WS=8 -> N=2048 windows x L=64 tokens, NH=4, hd=128.

typedef __attribute__((ext_vector_type(8))) short s16x8;   // 8 bf16 (4 VGPR)
typedef __attribute__((ext_vector_type(4))) float f32x4;   // MFMA C/D

#define C_TOT 512
#define HWIMG 128
#define CH_STRIDE (HWIMG * HWIMG) /* 16384 */

// ---- LDS layout (byte offsets) ----
#define XWO   0        // xw  [tok 64][c 512]  bf16, row 1024B, swz ((tok&7)<<4)
#define QO    65536    // Q   [tok 64][d 128]  bf16, row 256B,  swz ((tok&7)<<4)
#define KO    81920    // K   same as Q
#define VO    98304    // V^T [d 128][tok 64]  bf16, row 128B,  swz ((d&7)<<4)
#define PO    114688   // P   [tq 64][tk 64]   bf16, row 128B,  swz ((tq&7)<<4)
#define CTXO  122880   // ctx [tq 64][d 128]   bf16, row 256B,  swz ((tq&7)<<4)
#define DENO  139264   // 64 x f32 (1/rowsum)
#define LDSB  139520

__device__ __forceinline__ unsigned short f2bf(float f) {
  unsigned u = __float_as_uint(f);
  u += 0x7FFFu + ((u >> 16) & 1u);       // RNE
  return (unsigned short)(u >> 16);
}

__global__ void conv_w_kernel(const float* __restrict__ w_in,
                              const float* __restrict__ w_out,
                              unsigned short* __restrict__ wbf) {
  int i = blockIdx.x * blockDim.x + threadIdx.x;   // grid covers exactly 1048576
  const int NIN = 3 * C_TOT * C_TOT;               // 786432
  float v = (i < NIN) ? w_in[i] : w_out[i - NIN];
  wbf[i] = f2bf(v);
}

__global__ void __launch_bounds__(512, 2)
local_attn_kernel(const float* __restrict__ x,
                  const float* __restrict__ bin,
                  const float* __restrict__ bout,
                  const unsigned short* __restrict__ wi,   // w_in bf16 [1536][512]
                  const unsigned short* __restrict__ wo,   // w_out bf16 [512][512]
                  float* __restrict__ out) {
  __shared__ __align__(16) unsigned char sm[LDSB];

  const int tid  = threadIdx.x;
  const int wv   = tid >> 6;      // wave 0..7
  const int lane = tid & 63;
  const int l15  = lane & 15;
  const int qd   = lane >> 4;     // quad 0..3
  const int swA  = (l15 & 7) << 4;

  const int n  = blockIdx.x;      // window id = b*256 + hw*16 + ww
  const int bb = n >> 8;
  const int hw = (n >> 4) & 15;
  const int ww = n & 15;
  const size_t wbase = (size_t)bb * C_TOT * CH_STRIDE
                     + (size_t)(hw * 8) * HWIMG + (size_t)(ww * 8);

  // ---------------- stage xw (64 tok x 512 ch) -> LDS bf16 ----------------
  {
    const int tok = tid & 63;
    const int oct = tid >> 6;               // 0..7
    const int r = tok >> 3, cc = tok & 7;
    const float* px = x + wbase + (size_t)r * HWIMG + cc;
#pragma unroll
    for (int g = 0; g < 8; ++g) {
      const int ch0 = (g * 8 + oct) * 8;    // covers 0,8,...,504
      float v[8];
#pragma unroll
      for (int j = 0; j < 8; ++j) v[j] = px[(size_t)(ch0 + j) * CH_STRIDE];
      s16x8 pk;
#pragma unroll
      for (int j = 0; j < 8; ++j) pk[j] = (short)f2bf(v[j]);
      *(s16x8*)(&sm[XWO + tok * 1024 + ((2 * ch0) ^ ((tok & 7) << 4))]) = pk;
    }
  }
  __syncthreads();

  // persistent out^T accumulators: wave wv owns odims [64*wv, 64*wv+64)
  f32x4 oacc[4][4];
#pragma unroll
  for (int a = 0; a < 4; ++a)
#pragma unroll
    for (int b2 = 0; b2 < 4; ++b2) oacc[a][b2] = (f32x4){0.f, 0.f, 0.f, 0.f};

  const float SCALE = 0.08838834764831845f;  // 1/sqrt(128)
  const float L2E   = 1.4426950408889634f;

  for (int h = 0; h < 4; ++h) {
    // ================= QKV:  D[e][tok] = sum_c w_in[e][c]*xw[tok][c] ======
    // wave wv owns head-slice dims [48*wv, 48*wv+48): 3 M-tiles x 4 N-tiles
    f32x4 acc[3][4];
#pragma unroll
    for (int a = 0; a < 3; ++a)
#pragma unroll
      for (int b2 = 0; b2 < 4; ++b2) acc[a][b2] = (f32x4){0.f, 0.f, 0.f, 0.f};

    const unsigned short* wrow[3];
    int typ[3], w128s[3];
#pragma unroll
    for (int mi = 0; mi < 3; ++mi) {
      const int d0 = 48 * wv + 16 * mi;     // slice dim base (tile inside one type)
      const int t = d0 >> 7;                // 0=Q 1=K 2=V
      const int w128 = d0 & 127;
      typ[mi] = t; w128s[mi] = w128;
      const int eg0 = t * 512 + h * 128 + w128;   // global w_in row base
      wrow[mi] = wi + (size_t)(eg0 + l15) * 512;
    }
#pragma unroll 2
    for (int ks = 0; ks < 16; ++ks) {
      const int c0 = 32 * ks + 8 * qd;
      s16x8 a[3];
#pragma unroll
      for (int mi = 0; mi < 3; ++mi) a[mi] = *(const s16x8*)(wrow[mi] + c0);
      s16x8 bx[4];
#pragma unroll
      for (int ni = 0; ni < 4; ++ni) {
        const int tok = 16 * ni + l15;
        bx[ni] = *(const s16x8*)(&sm[XWO + tok * 1024 + ((2 * c0) ^ swA)]);
      }
#pragma unroll
      for (int mi = 0; mi < 3; ++mi)
#pragma unroll
        for (int ni = 0; ni < 4; ++ni)
          acc[mi][ni] = __builtin_amdgcn_mfma_f32_16x16x32_bf16(a[mi], bx[ni], acc[mi][ni], 0, 0, 0);
    }
    // write Q/K -> [tok][d] (packed b64), V -> [d][tok] (b16 scatter)
#pragma unroll
    for (int mi = 0; mi < 3; ++mi) {
      const int t = typ[mi], w128 = w128s[mi];
      const int eg0 = t * 512 + h * 128 + w128 + 4 * qd;
      const float bi0 = bin[eg0], bi1 = bin[eg0 + 1], bi2 = bin[eg0 + 2], bi3 = bin[eg0 + 3];
#pragma unroll
      for (int ni = 0; ni < 4; ++ni) {
        const int tok = 16 * ni + l15;
        const unsigned short h0 = f2bf(acc[mi][ni][0] + bi0);
        const unsigned short h1 = f2bf(acc[mi][ni][1] + bi1);
        const unsigned short h2 = f2bf(acc[mi][ni][2] + bi2);
        const unsigned short h3 = f2bf(acc[mi][ni][3] + bi3);
        if (t < 2) {
          const unsigned lo = (unsigned)h0 | ((unsigned)h1 << 16);
          const unsigned hi = (unsigned)h2 | ((unsigned)h3 << 16);
          const unsigned long long pk = (unsigned long long)lo | ((unsigned long long)hi << 32);
          const int base = (t == 0) ? QO : KO;
          *(unsigned long long*)(&sm[base + tok * 256 + ((2 * (w128 + 4 * qd)) ^ swA)]) = pk;
        } else {
          const int vd = w128 + 4 * qd;
          *(unsigned short*)(&sm[VO + (vd    ) * 128 + ((2 * tok) ^ (((vd    ) & 7) << 4))]) = h0;
          *(unsigned short*)(&sm[VO + (vd + 1) * 128 + ((2 * tok) ^ (((vd + 1) & 7) << 4))]) = h1;
          *(unsigned short*)(&sm[VO + (vd + 2) * 128 + ((2 * tok) ^ (((vd + 2) & 7) << 4))]) = h2;
          *(unsigned short*)(&sm[VO + (vd + 3) * 128 + ((2 * tok) ^ (((vd + 3) & 7) << 4))]) = h3;
        }
      }
    }
    __syncthreads();

    // ================= S = Q K^T, softmax (waves 0..3, full rows) =========
    if (wv < 4) {
      f32x4 s[4];
#pragma unroll
      for (int a = 0; a < 4; ++a) s[a] = (f32x4){0.f, 0.f, 0.f, 0.f};
      const int tqa = 16 * wv + l15;
#pragma unroll
      for (int ks = 0; ks < 4; ++ks) {
        const int c0 = 32 * ks + 8 * qd;
        const s16x8 aq = *(const s16x8*)(&sm[QO + tqa * 256 + ((2 * c0) ^ swA)]);
#pragma unroll
        for (int ni = 0; ni < 4; ++ni) {
          const int tk = 16 * ni + l15;
          const s16x8 bk = *(const s16x8*)(&sm[KO + tk * 256 + ((2 * c0) ^ swA)]);
          s[ni] = __builtin_amdgcn_mfma_f32_16x16x32_bf16(aq, bk, s[ni], 0, 0, 0);
        }
      }
      float sv[4][4];
#pragma unroll
      for (int ni = 0; ni < 4; ++ni)
#pragma unroll
        for (int i = 0; i < 4; ++i) sv[ni][i] = s[ni][i] * SCALE;
      float m[4];
#pragma unroll
      for (int i = 0; i < 4; ++i)
        m[i] = fmaxf(fmaxf(sv[0][i], sv[1][i]), fmaxf(sv[2][i], sv[3][i]));
#pragma unroll
      for (int d = 1; d < 16; d <<= 1)
#pragma unroll
        for (int i = 0; i < 4; ++i) m[i] = fmaxf(m[i], __shfl_xor(m[i], d));
      float p[4][4], sum[4] = {0.f, 0.f, 0.f, 0.f};
#pragma unroll
      for (int ni = 0; ni < 4; ++ni)
#pragma unroll
        for (int i = 0; i < 4; ++i) {
          p[ni][i] = exp2f((sv[ni][i] - m[i]) * L2E);
          sum[i] += p[ni][i];
        }
#pragma unroll
      for (int d = 1; d < 16; d <<= 1)
#pragma unroll
        for (int i = 0; i < 4; ++i) sum[i] += __shfl_xor(sum[i], d);
#pragma unroll
      for (int ni = 0; ni < 4; ++ni)
#pragma unroll
        for (int i = 0; i < 4; ++i) {
          const int tqr = 16 * wv + 4 * qd + i;
          const int tk = 16 * ni + l15;
          *(unsigned short*)(&sm[PO + tqr * 128 + ((2 * tk) ^ ((tqr & 7) << 4))]) = f2bf(p[ni][i]);
        }
      if (l15 == 0) {
#pragma unroll
        for (int i = 0; i < 4; ++i) {
          const int tqr = 16 * wv + 4 * qd + i;
          *(float*)(&sm[DENO + 4 * tqr]) = 1.0f / sum[i];
        }
      }
    }
    __syncthreads();

    // ================= PV: ctx[tq][vd] = sum_tk P[tq][tk] V[tk][vd] =======
    {
      const int mq = wv >> 1;              // tq tile
      const int nb = (wv & 1) * 4;         // vd tile base
      f32x4 cacc[4];
#pragma unroll
      for (int a = 0; a < 4; ++a) cacc[a] = (f32x4){0.f, 0.f, 0.f, 0.f};
      const int tqa = 16 * mq + l15;
#pragma unroll
      for (int ks = 0; ks < 2; ++ks) {
        const int c0 = 32 * ks + 8 * qd;
        const s16x8 ap = *(const s16x8*)(&sm[PO + tqa * 128 + ((2 * c0) ^ swA)]);
#pragma unroll
        for (int j = 0; j < 4; ++j) {
          const int vd = 16 * (nb + j) + l15;
          const s16x8 bv = *(const s16x8*)(&sm[VO + vd * 128 + ((2 * c0) ^ swA)]);
          cacc[j] = __builtin_amdgcn_mfma_f32_16x16x32_bf16(ap, bv, cacc[j], 0, 0, 0);
        }
      }
      float inv[4];
#pragma unroll
      for (int i = 0; i < 4; ++i)
        inv[i] = *(const float*)(&sm[DENO + 4 * (16 * mq + 4 * qd + i)]);
#pragma unroll
      for (int j = 0; j < 4; ++j)
#pragma unroll
        for (int i = 0; i < 4; ++i) {
          const int tqr = 16 * mq + 4 * qd + i;
          const int vd = 16 * (nb + j) + l15;
          *(unsigned short*)(&sm[CTXO + tqr * 256 + ((2 * vd) ^ ((tqr & 7) << 4))]) =
              f2bf(cacc[j][i] * inv[i]);
        }
    }
    __syncthreads();

    // ============ OUT partial: out^T[od][tok] += w_out[od][:]*ctx =========
    {
#pragma unroll
      for (int ks = 0; ks < 4; ++ks) {
        const int c0 = 32 * ks + 8 * qd;          // cdim within head
        s16x8 a[4];
#pragma unroll
        for (int mo = 0; mo < 4; ++mo) {
          const int od = 64 * wv + 16 * mo + l15;
          a[mo] = *(const s16x8*)(&wo[(size_t)od * 512 + 128 * h + c0]);
        }
        s16x8 bc[4];
#pragma unroll
        for (int ni = 0; ni < 4; ++ni) {
          const int tok = 16 * ni + l15;
          bc[ni] = *(const s16x8*)(&sm[CTXO + tok * 256 + ((2 * c0) ^ swA)]);
        }
#pragma unroll
        for (int mo = 0; mo < 4; ++mo)
#pragma unroll
          for (int ni = 0; ni < 4; ++ni)
            oacc[mo][ni] = __builtin_amdgcn_mfma_f32_16x16x32_bf16(a[mo], bc[ni], oacc[mo][ni], 0, 0, 0);
      }
    }
    // no barrier: next head's QKV touches only XW(read)/QKV-lds(write),
    // which OUT does not read; cross-wave safety via next head's barriers.
  }

  // ---------------- final store (+ b_out), window merge -------------------
#pragma unroll
  for (int mo = 0; mo < 4; ++mo) {
    const int od0 = 64 * wv + 16 * mo + 4 * qd;
    float bo[4];
#pragma unroll
    for (int i = 0; i < 4; ++i) bo[i] = bout[od0 + i];
#pragma unroll
    for (int ni = 0; ni < 4; ++ni) {
      const int tok = 16 * ni + l15;
      const int r = tok >> 3, cc = tok & 7;
#pragma unroll
      for (int i = 0; i < 4; ++i) {
        out[wbase + (size_t)(od0 + i) * CH_STRIDE + (size_t)r * HWIMG + cc] =
            oacc[mo][ni][i] + bo[i];
      }
    }
  }
}

extern "C" void kernel_launch(void* const* d_in, const int* in_sizes, int n_in,
                              void* d_out, int out_size, void* d_ws, size_t ws_size,
                              hipStream_t stream) {
  const float* x     = (const float*)d_in[0];
  const float* w_in  = (const float*)d_in[1];
  const float* b_in  = (const float*)d_in[2];
  const float* w_out = (const float*)d_in[3];
  const float* b_out = (const float*)d_in[4];
  float* out = (float*)d_out;
  unsigned short* wbf = (unsigned short*)d_ws;   // 1048576 bf16 = 2 MB

  conv_w_kernel<<<4096, 256, 0, stream>>>(w_in, w_out, wbf);
  local_attn_kernel<<<2048, 512, 0, stream>>>(x, b_in, b_out, wbf, wbf + 786432, out);
}